// Round 5
// baseline (24.259 us; speedup 1.0000x reference)
//
#include <hip/hip_runtime.h>

// Sparsemax over B=16384 equal segments of L=1024 contiguous fp32 elements.
// Persistent exact-fit grid: 8192 waves (32/CU), each wave processes TWO
// segments; both segments' loads are issued up front so segment B's HBM
// latency hides under segment A's compute. Reductions are DPP suffix-scans
// (VALU) + readlane; active-set count via ballot+popc (SALU). No LDS.

#define SEG_LEN 1024

typedef float f32x4 __attribute__((ext_vector_type(4)));

template <int CTRL>
static __device__ __forceinline__ float dpp_add(float v) {
  int d = __builtin_amdgcn_update_dpp(0, __float_as_int(v), CTRL, 0xF, 0xF, true);
  return v + __int_as_float(d);
}

template <int CTRL>
static __device__ __forceinline__ float dpp_max(float v) {
  int iv = __float_as_int(v);
  int d = __builtin_amdgcn_update_dpp(iv, iv, CTRL, 0xF, 0xF, false);
  return fmaxf(v, __int_as_float(d));
}

static __device__ __forceinline__ float wave_sum(float v) {
  v = dpp_add<0x111>(v);  // row_shr:1
  v = dpp_add<0x112>(v);  // row_shr:2
  v = dpp_add<0x114>(v);  // row_shr:4
  v = dpp_add<0x118>(v);  // row_shr:8
  v = dpp_add<0x142>(v);  // row_bcast:15
  v = dpp_add<0x143>(v);  // row_bcast:31
  return __int_as_float(__builtin_amdgcn_readlane(__float_as_int(v), 63));
}

static __device__ __forceinline__ float wave_max(float v) {
  v = dpp_max<0x111>(v);
  v = dpp_max<0x112>(v);
  v = dpp_max<0x114>(v);
  v = dpp_max<0x118>(v);
  v = dpp_max<0x142>(v);
  v = dpp_max<0x143>(v);
  return __int_as_float(__builtin_amdgcn_readlane(__float_as_int(v), 63));
}

// Process one segment already resident in registers; write result.
static __device__ __forceinline__ void process_seg(const f32x4 v[4],
                                                   float* __restrict__ outp,
                                                   int lane) {
  float m = fmaxf(fmaxf(v[0].x, v[0].y), fmaxf(v[0].z, v[0].w));
#pragma unroll
  for (int j = 1; j < 4; ++j)
    m = fmaxf(m, fmaxf(fmaxf(v[j].x, v[j].y), fmaxf(v[j].z, v[j].w)));
  m = wave_max(m);

  float xs[16];
#pragma unroll
  for (int j = 0; j < 4; ++j) {
    xs[j * 4 + 0] = v[j].x - m;
    xs[j * 4 + 1] = v[j].y - m;
    xs[j * 4 + 2] = v[j].z - m;
    xs[j * 4 + 3] = v[j].w - m;
  }

  // Michelot from tau0 = -1 (f(-1) >= 1): tau += (S-1)/cnt, active set
  // shrinks monotonically; count-stable => tau exact for final set.
  float tau = -1.0f;
  int cprev = -1;
  for (int it = 0; it < 32; ++it) {
    float S = 0.0f;
    int cnt = 0;
#pragma unroll
    for (int e = 0; e < 16; ++e) {
      const float t = xs[e] - tau;
      S += fmaxf(t, 0.0f);
      cnt += (int)__popcll(__ballot(t > 0.0f));
    }
    S = wave_sum(S);
    tau = tau + (S - 1.0f) * __builtin_amdgcn_rcpf((float)cnt);
    if (cnt == cprev) break;
    cprev = cnt;
  }

  f32x4* __restrict__ o = reinterpret_cast<f32x4*>(outp);
#pragma unroll
  for (int j = 0; j < 4; ++j) {
    f32x4 w;
    w.x = fmaxf(xs[j * 4 + 0] - tau, 0.0f);
    w.y = fmaxf(xs[j * 4 + 1] - tau, 0.0f);
    w.z = fmaxf(xs[j * 4 + 2] - tau, 0.0f);
    w.w = fmaxf(xs[j * 4 + 3] - tau, 0.0f);
    __builtin_nontemporal_store(w, &o[j * 64 + lane]);
  }
}

__global__ __launch_bounds__(256) void sparsemax_wave_kernel(
    const float* __restrict__ x, float* __restrict__ out, int nseg) {
  const int nwaves = (int)((gridDim.x * blockDim.x) >> 6);       // 8192
  const int wid    = (int)((blockIdx.x * blockDim.x + threadIdx.x) >> 6);
  const int lane   = (int)(threadIdx.x & 63);

  const int sA = wid;           // first segment
  const int sB = wid + nwaves;  // second segment (in-flight during A compute)
  if (sA >= nseg) return;
  const bool hasB = (sB < nseg);

  const f32x4* __restrict__ xa =
      reinterpret_cast<const f32x4*>(x + (size_t)sA * SEG_LEN);
  const f32x4* __restrict__ xb =
      reinterpret_cast<const f32x4*>(x + (size_t)(hasB ? sB : sA) * SEG_LEN);

  f32x4 va[4], vb[4];
#pragma unroll
  for (int j = 0; j < 4; ++j) va[j] = xa[j * 64 + lane];
#pragma unroll
  for (int j = 0; j < 4; ++j) vb[j] = xb[j * 64 + lane];   // prefetched

  process_seg(va, out + (size_t)sA * SEG_LEN, lane);
  if (hasB) process_seg(vb, out + (size_t)sB * SEG_LEN, lane);
}

extern "C" void kernel_launch(void* const* d_in, const int* in_sizes, int n_in,
                              void* d_out, int out_size, void* d_ws, size_t ws_size,
                              hipStream_t stream) {
  const float* x = (const float*)d_in[0];
  float* out = (float*)d_out;
  const int n = in_sizes[0];
  const int nseg = n / SEG_LEN;                  // 16384
  // Exact fit: 2048 blocks x 4 waves = 8192 waves = 32 waves/CU on 256 CUs;
  // each wave handles 2 segments.
  const int blocks = (nseg + 7) / 8;             // 2048
  sparsemax_wave_kernel<<<blocks, 256, 0, stream>>>(x, out, nseg);
}